// Round 12
// baseline (1997.284 us; speedup 1.0000x reference)
//
#include <hip/hip_runtime.h>
#include <hip/hip_bf16.h>

#define NNODES 4096
#define NBATCH 4096
#define NBLK 8
#define LN_EPS 1e-5f
#define NGRID 256u

typedef __attribute__((ext_vector_type(8))) short short8;
typedef __attribute__((ext_vector_type(4))) float f32x4;
typedef __attribute__((ext_vector_type(4))) unsigned short u16x4;
typedef unsigned short u16;

__device__ __forceinline__ u16 bf16_rn(float f) {
  unsigned int u = __builtin_bit_cast(unsigned int, f);
  u += 0x7fffu + ((u >> 16) & 1u);
  return (u16)(u >> 16);
}

__device__ __forceinline__ float bf16_to_f(u16 h) {
  unsigned int u = ((unsigned int)h) << 16;
  return __builtin_bit_cast(float, u);
}

__device__ __forceinline__ void load_lds16(const void* g, void* l) {
  __builtin_amdgcn_global_load_lds((const __attribute__((address_space(1))) void*)g,
                                   (__attribute__((address_space(3))) void*)l,
                                   16, 0, 0);
}

// ---- device-scope grid barrier (all 256 blocks co-resident: 1 block/CU by LDS) ----
__device__ __forceinline__ void grid_barrier(unsigned* cnt, unsigned* gen) {
  __syncthreads();                     // drains vmcnt/lgkm for the whole block
  if (threadIdx.x == 0) {
    __threadfence();                   // release: make our writes device-visible
    unsigned g = __hip_atomic_load(gen, __ATOMIC_RELAXED, __HIP_MEMORY_SCOPE_AGENT);
    unsigned a = __hip_atomic_fetch_add(cnt, 1u, __ATOMIC_ACQ_REL, __HIP_MEMORY_SCOPE_AGENT);
    if (a == NGRID - 1u) {
      __hip_atomic_store(cnt, 0u, __ATOMIC_RELAXED, __HIP_MEMORY_SCOPE_AGENT);
      __hip_atomic_fetch_add(gen, 1u, __ATOMIC_RELEASE, __HIP_MEMORY_SCOPE_AGENT);
    } else {
      while (__hip_atomic_load(gen, __ATOMIC_ACQUIRE, __HIP_MEMORY_SCOPE_AGENT) == g)
        __builtin_amdgcn_s_sleep(2);
    }
    __threadfence();                   // acquire: invalidate stale cache lines
  }
  __syncthreads();
}

// ---- merged prep for layer 0: blocks [0,16384) convert W0; [16384,20480) LN(x f32) ----
__global__ __launch_bounds__(256) void prep_kernel(const float* __restrict__ W,
                                                   u16* __restrict__ Wb,
                                                   const float* __restrict__ xin,
                                                   const float* __restrict__ g,
                                                   const float* __restrict__ bt,
                                                   u16* __restrict__ lnout) {
  __shared__ float sh[8];
  int t = threadIdx.x;
  if (blockIdx.x < 16384) {
    int idx = blockIdx.x * 256 + t;
    float4 v = ((const float4*)W)[idx];
    u16x4 o;
    o[0] = bf16_rn(v.x); o[1] = bf16_rn(v.y); o[2] = bf16_rn(v.z); o[3] = bf16_rn(v.w);
    ((u16x4*)Wb)[idx] = o;
    return;
  }
  int row = blockIdx.x - 16384;
  float f[16];
  float s = 0.f, ss = 0.f;
  const float4* xr = (const float4*)(xin + (size_t)row * NNODES);
#pragma unroll
  for (int q = 0; q < 4; ++q) {
    float4 v = xr[q * 256 + t];
    f[q * 4 + 0] = v.x; f[q * 4 + 1] = v.y; f[q * 4 + 2] = v.z; f[q * 4 + 3] = v.w;
    s  += v.x + v.y + v.z + v.w;
    ss += v.x * v.x + v.y * v.y + v.z * v.z + v.w * v.w;
  }
#pragma unroll
  for (int off = 32; off >= 1; off >>= 1) {
    s  += __shfl_xor(s, off, 64);
    ss += __shfl_xor(ss, off, 64);
  }
  int wid = t >> 6, lane = t & 63;
  if (lane == 0) { sh[wid] = s; sh[wid + 4] = ss; }
  __syncthreads();
  s  = sh[0] + sh[1] + sh[2] + sh[3];
  ss = sh[4] + sh[5] + sh[6] + sh[7];
  float mu  = s * (1.f / NNODES);
  float var = ss * (1.f / NNODES) - mu * mu;
  float rs  = rsqrtf(var + LN_EPS);
  u16x4* o = (u16x4*)(lnout + (size_t)row * NNODES);
  const float4* gv = (const float4*)g;
  const float4* bv = (const float4*)bt;
#pragma unroll
  for (int q = 0; q < 4; ++q) {
    int i = q * 256 + t;
    float4 gg = gv[i], bb = bv[i];
    u16x4 ov;
    ov[0] = bf16_rn((f[q * 4 + 0] - mu) * rs * gg.x + bb.x);
    ov[1] = bf16_rn((f[q * 4 + 1] - mu) * rs * gg.y + bb.y);
    ov[2] = bf16_rn((f[q * 4 + 2] - mu) * rs * gg.z + bb.z);
    ov[3] = bf16_rn((f[q * 4 + 3] - mu) * rs * gg.w + bb.w);
    o[i] = ov;
  }
}

// ---- in-mega LN pass: 16 rows/block, 2 rows/wave, 64 bf16/lane ----
__device__ __forceinline__ void ln_pass(const u16* __restrict__ y,
                                        const float* __restrict__ g,
                                        const float* __restrict__ bt,
                                        u16* __restrict__ lnout,
                                        int bid, int wid, int lane) {
#pragma unroll
  for (int rr = 0; rr < 2; ++rr) {
    int row = bid * 16 + wid * 2 + rr;
    const u16* xr = y + (size_t)row * NNODES + lane * 8;
    short8 v[8];
    float s = 0.f, ss = 0.f;
#pragma unroll
    for (int q = 0; q < 8; ++q) {
      v[q] = *(const short8*)(xr + q * 512);
#pragma unroll
      for (int j = 0; j < 8; ++j) {
        float f = bf16_to_f((u16)v[q][j]);
        s += f; ss += f * f;
      }
    }
#pragma unroll
    for (int off = 32; off >= 1; off >>= 1) {
      s  += __shfl_xor(s, off, 64);
      ss += __shfl_xor(ss, off, 64);
    }
    float mu  = s * (1.f / NNODES);
    float var = ss * (1.f / NNODES) - mu * mu;
    float rs  = rsqrtf(var + LN_EPS);
    u16* o = lnout + (size_t)row * NNODES + lane * 8;
#pragma unroll
    for (int q = 0; q < 8; ++q) {
      int base = lane * 8 + q * 512;
      float4 g0 = *(const float4*)(g + base), g1 = *(const float4*)(g + base + 4);
      float4 b0 = *(const float4*)(bt + base), b1 = *(const float4*)(bt + base + 4);
      short8 sv;
      sv[0] = (short)bf16_rn((bf16_to_f((u16)v[q][0]) - mu) * rs * g0.x + b0.x);
      sv[1] = (short)bf16_rn((bf16_to_f((u16)v[q][1]) - mu) * rs * g0.y + b0.y);
      sv[2] = (short)bf16_rn((bf16_to_f((u16)v[q][2]) - mu) * rs * g0.z + b0.z);
      sv[3] = (short)bf16_rn((bf16_to_f((u16)v[q][3]) - mu) * rs * g0.w + b0.w);
      sv[4] = (short)bf16_rn((bf16_to_f((u16)v[q][4]) - mu) * rs * g1.x + b1.x);
      sv[5] = (short)bf16_rn((bf16_to_f((u16)v[q][5]) - mu) * rs * g1.y + b1.y);
      sv[6] = (short)bf16_rn((bf16_to_f((u16)v[q][6]) - mu) * rs * g1.z + b1.z);
      sv[7] = (short)bf16_rn((bf16_to_f((u16)v[q][7]) - mu) * rs * g1.w + b1.w);
      *(short8*)(o + q * 512) = sv;
    }
  }
}

// ---- 256x256 bf16 NT GEMM body (round-11 schedule, unchanged) ----
#define VMC(N) asm volatile("s_waitcnt vmcnt(" #N ")" ::: "memory")

#define STAGE_A(T, H)                                                          \
  { load_lds16(Asrc0 + (size_t)((H) * 128) * Kdim + (T) * 64,                  \
               ldsA + ((T) & 1) * 16384 + (H) * 8192 + tid * 8);               \
    load_lds16(Asrc0 + (size_t)((H) * 128 + 64) * Kdim + (T) * 64,             \
               ldsA + ((T) & 1) * 16384 + (H) * 8192 + 4096 + tid * 8); }

#define STAGE_B(T, H)                                                          \
  { load_lds16(Bsrc0 + (size_t)((H) * 128) * Kdim + (T) * 64,                  \
               ldsB + ((T) & 1) * 16384 + (H) * 8192 + tid * 8);               \
    load_lds16(Bsrc0 + (size_t)((H) * 128 + 64) * Kdim + (T) * 64,             \
               ldsB + ((T) & 1) * 16384 + (H) * 8192 + 4096 + tid * 8); }

#define CVSTORE(SRC, CIDX)                                                     \
  { u16x4 o_;                                                                  \
    o_[0] = bf16_rn(SRC[0]); o_[1] = bf16_rn(SRC[1]);                          \
    o_[2] = bf16_rn(SRC[2]); o_[3] = bf16_rn(SRC[3]);                          \
    *(u16x4*)(Wnd + cvoff + (size_t)(CIDX) * 2048) = o_; }

#define CONVP2                                                                 \
  { if (CONVON && t >= 1 && t <= 16) {                                         \
      __builtin_amdgcn_sched_barrier(0);                                       \
      CVSTORE(cvA, 2 * (t - 1))                                                \
      CVSTORE(cvB, 2 * (t - 1) + 1)                                            \
    }                                                                          \
    if (CONVON && t < 16) {                                                    \
      const float* cpa_ = Wns + cvoff + (size_t)(2 * t) * 2048;                \
      const float* cpb_ = Wns + cvoff + (size_t)(2 * t + 1) * 2048;            \
      asm volatile("global_load_dwordx4 %0, %2, off\n\t"                       \
                   "global_load_dwordx4 %1, %3, off"                           \
                   : "=&v"(cvA), "=&v"(cvB) : "v"(cpa_), "v"(cpb_)             \
                   : "memory");                                                \
    } }

#define VMP3                                                                   \
  { if (CONVON) {                                                              \
      if (t == 0 || t == 16) { VMC(4); }                                       \
      else if (t < 16)       { VMC(6); }                                       \
      else                   { VMC(2); }                                       \
    } else { VMC(2); } }

#define PH1(KT, MH, NH, STAGE_STMT, VM_STMT)                                   \
  {                                                                            \
    const u16* Ab = ldsA + ((KT) & 1) * 16384 + aBase + (MH) * 4096;           \
    const u16* Bb = ldsB + ((KT) & 1) * 16384 + bBase + (NH) * 2048;           \
    if ((NH) == 0) {                                                           \
      _Pragma("unroll") for (int mi = 0; mi < 4; ++mi) {                       \
        afr[mi][0] = *(const short8*)(Ab + mi * 1024 + gk0);                   \
        afr[mi][1] = *(const short8*)(Ab + mi * 1024 + gk1);                   \
      }                                                                        \
    }                                                                          \
    if ((MH) == 0) {                                                           \
      _Pragma("unroll") for (int ni = 0; ni < 2; ++ni) {                       \
        bfr[NH][ni][0] = *(const short8*)(Bb + ni * 1024 + gk0);               \
        bfr[NH][ni][1] = *(const short8*)(Bb + ni * 1024 + gk1);               \
      }                                                                        \
    }                                                                          \
    STAGE_STMT;                                                                \
    if ((NH) == 0 && (MH) == 0)                                                \
      asm volatile("s_waitcnt lgkmcnt(8)" ::: "memory");                       \
    VM_STMT;                                                                   \
    __builtin_amdgcn_s_barrier();                                              \
    asm volatile("s_waitcnt lgkmcnt(0)" ::: "memory");                         \
    __builtin_amdgcn_sched_barrier(0);                                         \
    __builtin_amdgcn_s_setprio(1);                                             \
    _Pragma("unroll") for (int mi = 0; mi < 4; ++mi)                           \
      _Pragma("unroll") for (int ni = 0; ni < 2; ++ni) {                       \
        acc[(MH) * 4 + mi][(NH) * 2 + ni] =                                    \
          __builtin_amdgcn_mfma_f32_16x16x32_bf16(afr[mi][0], bfr[NH][ni][0],  \
            acc[(MH) * 4 + mi][(NH) * 2 + ni], 0, 0, 0);                       \
        acc[(MH) * 4 + mi][(NH) * 2 + ni] =                                    \
          __builtin_amdgcn_mfma_f32_16x16x32_bf16(afr[mi][1], bfr[NH][ni][1],  \
            acc[(MH) * 4 + mi][(NH) * 2 + ni], 0, 0, 0);                       \
      }                                                                        \
    __builtin_amdgcn_s_setprio(0);                                             \
  }

template <bool OUTF32, bool CONVON>
__device__ __forceinline__ void gemm_body(const u16* __restrict__ A,
                                          const u16* __restrict__ B,
                                          const float* __restrict__ bias,
                                          const float* __restrict__ slope,
                                          void* __restrict__ Cv,
                                          const float* __restrict__ Wns,
                                          u16* __restrict__ Wnd,
                                          u16* lds) {
  constexpr int Kdim = NNODES;
  u16* ldsA = lds;
  u16* ldsB = lds + 32768;

  const int tid  = threadIdx.x;
  const int lane = tid & 63;
  const int wid  = tid >> 6;
  const int wr   = wid >> 2;
  const int wc   = wid & 3;

  int bid = blockIdx.x;
  int swz = (bid & 7) * 32 + (bid >> 3);
  const int brow = (swz >> 4) * 256;
  const int bcol = (swz & 15) * 256;

  const int srow = tid >> 3;
  const int sg   = ((tid & 7) ^ (srow & 7)) * 8;
  const u16* Asrc0 = A + (size_t)(brow + srow) * Kdim + sg;
  const u16* Bsrc0 = B + (size_t)(bcol + srow) * Kdim + sg;

  const int r16 = lane & 15, kq = lane >> 4;
  const int g0  = kq ^ (r16 & 7);
  const int gk0 = g0 * 8, gk1 = (g0 ^ 4) * 8;
  const int aBase = wr * 8192 + r16 * 64;
  const int bBase = (wc >> 1) * 8192 + ((wc & 1) * 64 + r16) * 64;

  const size_t cvoff = (size_t)bid * 65536 + tid * 4;
  f32x4 cvA, cvB;

  f32x4 acc[8][4] = {};
  short8 afr[4][2], bfr[2][2][2];

  STAGE_B(0, 0) STAGE_B(0, 1) STAGE_A(0, 0) STAGE_A(0, 1) STAGE_B(1, 0) STAGE_B(1, 1)
  VMC(4);
  __builtin_amdgcn_s_barrier();

  for (int t = 0; t < 31; ++t) {
    const int T = 2 * t;
    PH1(T,     0, 0, STAGE_A(T + 1, 0), ;)
    PH1(T,     0, 1, STAGE_A(T + 1, 1), ;)
    PH1(T,     1, 0, CONVP2,            ;)
    PH1(T,     1, 1, STAGE_B(T + 2, 0), VMP3)
    PH1(T + 1, 0, 0, STAGE_B(T + 2, 1), ;)
    PH1(T + 1, 0, 1, STAGE_A(T + 2, 0), ;)
    PH1(T + 1, 1, 0, STAGE_A(T + 2, 1), ;)
    PH1(T + 1, 1, 1, { STAGE_B(T + 3, 0) STAGE_B(T + 3, 1) }, VMC(4))
  }
  PH1(62, 0, 0, STAGE_A(63, 0), ;)
  PH1(62, 0, 1, STAGE_A(63, 1), ;)
  PH1(62, 1, 0, ;, ;)
  PH1(62, 1, 1, ;, VMC(0))
  PH1(63, 0, 0, ;, ;)
  PH1(63, 0, 1, ;, ;)
  PH1(63, 1, 0, ;, ;)
  PH1(63, 1, 1, ;, ;)

  const int crow0 = brow + wr * 128 + (lane >> 4) * 4;
  const int ccol0 = bcol + wc * 64 + r16;
#pragma unroll
  for (int n = 0; n < 4; ++n) {
    int col = ccol0 + n * 16;
    float bv = bias[col], sv = slope[col];
#pragma unroll
    for (int m = 0; m < 8; ++m) {
      int row0 = crow0 + m * 16;
#pragma unroll
      for (int r = 0; r < 4; ++r) {
        float vv = acc[m][n][r] + bv;
        vv = vv < 0.f ? vv * sv : vv;
        if constexpr (OUTF32) {
          ((float*)Cv)[(size_t)(row0 + r) * NNODES + col] = vv;
        } else {
          ((u16*)Cv)[(size_t)(row0 + r) * NNODES + col] = bf16_rn(vv);
        }
      }
    }
  }
}

// ---- mega kernel: 8 x (LN + GEMM) with grid barriers ----
__global__ __launch_bounds__(512, 2) void mega_kernel(const float* __restrict__ W,
                                                      const float* __restrict__ ln_g,
                                                      const float* __restrict__ ln_b,
                                                      const float* __restrict__ b,
                                                      const float* __restrict__ slope,
                                                      u16* __restrict__ Wbuf0,
                                                      u16* __restrict__ Wbuf1,
                                                      u16* __restrict__ lnbuf,
                                                      u16* __restrict__ ybuf,
                                                      float* __restrict__ out,
                                                      unsigned* cnt, unsigned* gen) {
  __shared__ u16 lds[65536];
  const size_t WN = (size_t)NNODES * NNODES;
  const int bid = blockIdx.x;
  const int wid = threadIdx.x >> 6;
  const int lane = threadIdx.x & 63;

  // layer 0 (lnbuf/Wbuf0 from prep kernel)
  gemm_body<false, true>(lnbuf, Wbuf0, b, slope, (void*)ybuf, W + WN, Wbuf1, lds);
  grid_barrier(cnt, gen);

  for (int i = 1; i < 7; ++i) {
    ln_pass(ybuf, ln_g + (size_t)i * NNODES, ln_b + (size_t)i * NNODES, lnbuf, bid, wid, lane);
    grid_barrier(cnt, gen);
    const u16* Wc = (i & 1) ? Wbuf1 : Wbuf0;
    u16* Wn = (i & 1) ? Wbuf0 : Wbuf1;
    gemm_body<false, true>(lnbuf, Wc, b + (size_t)i * NNODES, slope + (size_t)i * NNODES,
                           (void*)ybuf, W + WN * (i + 1), Wn, lds);
    grid_barrier(cnt, gen);
  }

  // layer 7
  ln_pass(ybuf, ln_g + (size_t)7 * NNODES, ln_b + (size_t)7 * NNODES, lnbuf, bid, wid, lane);
  grid_barrier(cnt, gen);
  gemm_body<true, false>(lnbuf, Wbuf1, b + (size_t)7 * NNODES, slope + (size_t)7 * NNODES,
                         (void*)out, nullptr, nullptr, lds);
}

extern "C" void kernel_launch(void* const* d_in, const int* in_sizes, int n_in,
                              void* d_out, int out_size, void* d_ws, size_t ws_size,
                              hipStream_t stream) {
  const float* x     = (const float*)d_in[0];
  const float* ln_g  = (const float*)d_in[1];
  const float* ln_b  = (const float*)d_in[2];
  const float* W     = (const float*)d_in[3];
  const float* b     = (const float*)d_in[4];
  const float* slope = (const float*)d_in[5];
  float* out = (float*)d_out;

  char* ws = (char*)d_ws;
  u16* Wbuf0 = (u16*)ws;                                   // 32 MB
  u16* Wbuf1 = (u16*)(ws + (size_t)32 * 1024 * 1024);      // 32 MB
  u16* lnbuf = (u16*)(ws + (size_t)64 * 1024 * 1024);      // 32 MB
  u16* ybuf  = (u16*)(ws + (size_t)96 * 1024 * 1024);      // 32 MB

  // sync counters: ws tail if it fits, else d_out[0..1] (dead after last barrier;
  // layer-7 epilogue overwrites them ~100us after the final barrier release)
  const size_t used = (size_t)128 * 1024 * 1024;
  unsigned* sync = (ws_size >= used + 64) ? (unsigned*)(ws + used) : (unsigned*)d_out;
  hipMemsetAsync((void*)sync, 0, 8, stream);

  prep_kernel<<<dim3(16384 + NBATCH), dim3(256), 0, stream>>>(W, Wbuf0, x, ln_g, ln_b, lnbuf);
  mega_kernel<<<dim3(NGRID), dim3(512), 0, stream>>>(W, ln_g, ln_b, b, slope,
                                                     Wbuf0, Wbuf1, lnbuf, ybuf, out,
                                                     sync, sync + 1);
}

// Round 13
// 1041.772 us; speedup vs baseline: 1.9172x; 1.9172x over previous
//
#include <hip/hip_runtime.h>
#include <hip/hip_bf16.h>

#define NNODES 4096
#define NBATCH 4096
#define NBLK 8
#define LN_EPS 1e-5f

typedef __attribute__((ext_vector_type(8))) short short8;
typedef __attribute__((ext_vector_type(4))) float f32x4;
typedef __attribute__((ext_vector_type(4))) unsigned short u16x4;
typedef unsigned short u16;

__device__ __forceinline__ u16 bf16_rn(float f) {
  unsigned int u = __builtin_bit_cast(unsigned int, f);
  u += 0x7fffu + ((u >> 16) & 1u);
  return (u16)(u >> 16);
}

__device__ __forceinline__ float bf16_to_f(u16 h) {
  unsigned int u = ((unsigned int)h) << 16;
  return __builtin_bit_cast(float, u);
}

__device__ __forceinline__ void load_lds16(const void* g, void* l) {
  __builtin_amdgcn_global_load_lds((const __attribute__((address_space(1))) void*)g,
                                   (__attribute__((address_space(3))) void*)l,
                                   16, 0, 0);
}

// ---- merged prep for layer 0: blocks [0,16384) convert W0; [16384,20480) LN(x f32) ----
__global__ __launch_bounds__(256) void prep_kernel(const float* __restrict__ W,
                                                   u16* __restrict__ Wb,
                                                   const float* __restrict__ xin,
                                                   const float* __restrict__ g,
                                                   const float* __restrict__ bt,
                                                   u16* __restrict__ lnout) {
  __shared__ float sh[8];
  int t = threadIdx.x;
  if (blockIdx.x < 16384) {
    int idx = blockIdx.x * 256 + t;
    float4 v = ((const float4*)W)[idx];
    u16x4 o;
    o[0] = bf16_rn(v.x); o[1] = bf16_rn(v.y); o[2] = bf16_rn(v.z); o[3] = bf16_rn(v.w);
    ((u16x4*)Wb)[idx] = o;
    return;
  }
  int row = blockIdx.x - 16384;
  float f[16];
  float s = 0.f, ss = 0.f;
  const float4* xr = (const float4*)(xin + (size_t)row * NNODES);
#pragma unroll
  for (int q = 0; q < 4; ++q) {
    float4 v = xr[q * 256 + t];
    f[q * 4 + 0] = v.x; f[q * 4 + 1] = v.y; f[q * 4 + 2] = v.z; f[q * 4 + 3] = v.w;
    s  += v.x + v.y + v.z + v.w;
    ss += v.x * v.x + v.y * v.y + v.z * v.z + v.w * v.w;
  }
#pragma unroll
  for (int off = 32; off >= 1; off >>= 1) {
    s  += __shfl_xor(s, off, 64);
    ss += __shfl_xor(ss, off, 64);
  }
  int wid = t >> 6, lane = t & 63;
  if (lane == 0) { sh[wid] = s; sh[wid + 4] = ss; }
  __syncthreads();
  s  = sh[0] + sh[1] + sh[2] + sh[3];
  ss = sh[4] + sh[5] + sh[6] + sh[7];
  float mu  = s * (1.f / NNODES);
  float var = ss * (1.f / NNODES) - mu * mu;
  float rs  = rsqrtf(var + LN_EPS);
  u16x4* o = (u16x4*)(lnout + (size_t)row * NNODES);
  const float4* gv = (const float4*)g;
  const float4* bv = (const float4*)bt;
#pragma unroll
  for (int q = 0; q < 4; ++q) {
    int i = q * 256 + t;
    float4 gg = gv[i], bb = bv[i];
    u16x4 ov;
    ov[0] = bf16_rn((f[q * 4 + 0] - mu) * rs * gg.x + bb.x);
    ov[1] = bf16_rn((f[q * 4 + 1] - mu) * rs * gg.y + bb.y);
    ov[2] = bf16_rn((f[q * 4 + 2] - mu) * rs * gg.z + bb.z);
    ov[3] = bf16_rn((f[q * 4 + 3] - mu) * rs * gg.w + bb.w);
    o[i] = ov;
  }
}

// ---- row LayerNorm, bf16 input (layers 1..7) -> bf16 out ----
__global__ __launch_bounds__(256) void ln_bf16_kernel(const u16* __restrict__ x,
                                                      const float* __restrict__ g,
                                                      const float* __restrict__ bt,
                                                      u16* __restrict__ out) {
  int row = blockIdx.x;
  int t = threadIdx.x;
  const u16* xr = x + (size_t)row * NNODES;
  float f[2][8];
  float s = 0.f, ss = 0.f;
#pragma unroll
  for (int q = 0; q < 2; ++q) {
    short8 v = *(const short8*)(xr + q * 2048 + t * 8);
#pragma unroll
    for (int j = 0; j < 8; ++j) {
      float fv = bf16_to_f((u16)v[j]);
      f[q][j] = fv;
      s += fv; ss += fv * fv;
    }
  }
#pragma unroll
  for (int off = 32; off >= 1; off >>= 1) {
    s  += __shfl_xor(s, off, 64);
    ss += __shfl_xor(ss, off, 64);
  }
  __shared__ float sh[8];
  int wid = t >> 6, lane = t & 63;
  if (lane == 0) { sh[wid] = s; sh[wid + 4] = ss; }
  __syncthreads();
  s  = sh[0] + sh[1] + sh[2] + sh[3];
  ss = sh[4] + sh[5] + sh[6] + sh[7];
  float mu  = s * (1.f / NNODES);
  float var = ss * (1.f / NNODES) - mu * mu;
  float rs  = rsqrtf(var + LN_EPS);
  const float4* gv = (const float4*)g;
  const float4* bv = (const float4*)bt;
#pragma unroll
  for (int q = 0; q < 2; ++q) {
    int base = q * 2048 + t * 8;
    float4 g0 = gv[base / 4], g1 = gv[base / 4 + 1];
    float4 b0 = bv[base / 4], b1 = bv[base / 4 + 1];
    short8 sv;
    sv[0] = (short)bf16_rn((f[q][0] - mu) * rs * g0.x + b0.x);
    sv[1] = (short)bf16_rn((f[q][1] - mu) * rs * g0.y + b0.y);
    sv[2] = (short)bf16_rn((f[q][2] - mu) * rs * g0.z + b0.z);
    sv[3] = (short)bf16_rn((f[q][3] - mu) * rs * g0.w + b0.w);
    sv[4] = (short)bf16_rn((f[q][4] - mu) * rs * g1.x + b1.x);
    sv[5] = (short)bf16_rn((f[q][5] - mu) * rs * g1.y + b1.y);
    sv[6] = (short)bf16_rn((f[q][6] - mu) * rs * g1.z + b1.z);
    sv[7] = (short)bf16_rn((f[q][7] - mu) * rs * g1.w + b1.w);
    *(short8*)(out + (size_t)row * NNODES + base) = sv;
  }
}

// ---- 256x256 bf16 NT GEMM, 8 waves, BK=64, 2-dbuf, 8-phase, SINGLE barrier/phase ----
// (round-11 schedule, proven: absmax bit-stable across 5 rounds)
// Stage map: p0:A(T+1,0) p1:A(T+1,1) p2:conv-only p3:B(T+2,0) p4:B(T+2,1)
//            p5:A(T+2,0) p6:A(T+2,1) p7:B(T+3,0)+B(T+3,1)
// Certs: p3 VMC(2)/(4)/(6) certifies A(T+1)+conv-loads; p7 VMC(4) certifies
// A(T+2),B(T+2) (leaves B(T+3)x4 outstanding). Conv W(i+1) at p2: stores prev
// 2 chunks (retired by prev p7 VMC(4)) + 2 raw-asm loads.

#define VMC(N) asm volatile("s_waitcnt vmcnt(" #N ")" ::: "memory")

#define STAGE_A(T, H)                                                          \
  { load_lds16(Asrc0 + (size_t)((H) * 128) * Kdim + (T) * 64,                  \
               ldsA + ((T) & 1) * 16384 + (H) * 8192 + tid * 8);               \
    load_lds16(Asrc0 + (size_t)((H) * 128 + 64) * Kdim + (T) * 64,             \
               ldsA + ((T) & 1) * 16384 + (H) * 8192 + 4096 + tid * 8); }

#define STAGE_B(T, H)                                                          \
  { load_lds16(Bsrc0 + (size_t)((H) * 128) * Kdim + (T) * 64,                  \
               ldsB + ((T) & 1) * 16384 + (H) * 8192 + tid * 8);               \
    load_lds16(Bsrc0 + (size_t)((H) * 128 + 64) * Kdim + (T) * 64,             \
               ldsB + ((T) & 1) * 16384 + (H) * 8192 + 4096 + tid * 8); }

#define CVSTORE(SRC, CIDX)                                                     \
  { u16x4 o_;                                                                  \
    o_[0] = bf16_rn(SRC[0]); o_[1] = bf16_rn(SRC[1]);                          \
    o_[2] = bf16_rn(SRC[2]); o_[3] = bf16_rn(SRC[3]);                          \
    *(u16x4*)(Wnd + cvoff + (size_t)(CIDX) * 2048) = o_; }

#define CONVP2                                                                 \
  { if (CONVON && t >= 1 && t <= 16) {                                         \
      __builtin_amdgcn_sched_barrier(0);                                       \
      CVSTORE(cvA, 2 * (t - 1))                                                \
      CVSTORE(cvB, 2 * (t - 1) + 1)                                            \
    }                                                                          \
    if (CONVON && t < 16) {                                                    \
      const float* cpa_ = Wns + cvoff + (size_t)(2 * t) * 2048;                \
      const float* cpb_ = Wns + cvoff + (size_t)(2 * t + 1) * 2048;            \
      asm volatile("global_load_dwordx4 %0, %2, off\n\t"                       \
                   "global_load_dwordx4 %1, %3, off"                           \
                   : "=&v"(cvA), "=&v"(cvB) : "v"(cpa_), "v"(cpb_)             \
                   : "memory");                                                \
    } }

#define VMP3                                                                   \
  { if (CONVON) {                                                              \
      if (t == 0 || t == 16) { VMC(4); }                                       \
      else if (t < 16)       { VMC(6); }                                       \
      else                   { VMC(2); }                                       \
    } else { VMC(2); } }

#define PH1(KT, MH, NH, STAGE_STMT, VM_STMT)                                   \
  {                                                                            \
    const u16* Ab = ldsA + ((KT) & 1) * 16384 + aBase + (MH) * 4096;           \
    const u16* Bb = ldsB + ((KT) & 1) * 16384 + bBase + (NH) * 2048;           \
    if ((NH) == 0) {                                                           \
      _Pragma("unroll") for (int mi = 0; mi < 4; ++mi) {                       \
        afr[mi][0] = *(const short8*)(Ab + mi * 1024 + gk0);                   \
        afr[mi][1] = *(const short8*)(Ab + mi * 1024 + gk1);                   \
      }                                                                        \
    }                                                                          \
    if ((MH) == 0) {                                                           \
      _Pragma("unroll") for (int ni = 0; ni < 2; ++ni) {                       \
        bfr[NH][ni][0] = *(const short8*)(Bb + ni * 1024 + gk0);               \
        bfr[NH][ni][1] = *(const short8*)(Bb + ni * 1024 + gk1);               \
      }                                                                        \
    }                                                                          \
    STAGE_STMT;                                                                \
    if ((NH) == 0 && (MH) == 0)                                                \
      asm volatile("s_waitcnt lgkmcnt(8)" ::: "memory");                       \
    VM_STMT;                                                                   \
    __builtin_amdgcn_s_barrier();                                              \
    asm volatile("s_waitcnt lgkmcnt(0)" ::: "memory");                         \
    __builtin_amdgcn_sched_barrier(0);                                         \
    __builtin_amdgcn_s_setprio(1);                                             \
    _Pragma("unroll") for (int mi = 0; mi < 4; ++mi)                           \
      _Pragma("unroll") for (int ni = 0; ni < 2; ++ni) {                       \
        acc[(MH) * 4 + mi][(NH) * 2 + ni] =                                    \
          __builtin_amdgcn_mfma_f32_16x16x32_bf16(afr[mi][0], bfr[NH][ni][0],  \
            acc[(MH) * 4 + mi][(NH) * 2 + ni], 0, 0, 0);                       \
        acc[(MH) * 4 + mi][(NH) * 2 + ni] =                                    \
          __builtin_amdgcn_mfma_f32_16x16x32_bf16(afr[mi][1], bfr[NH][ni][1],  \
            acc[(MH) * 4 + mi][(NH) * 2 + ni], 0, 0, 0);                       \
      }                                                                        \
    __builtin_amdgcn_s_setprio(0);                                             \
  }

template <bool OUTF32, bool CONVON>
__global__ __launch_bounds__(512, 2) void gemm256_kernel(const u16* __restrict__ A,
                                                         const u16* __restrict__ B,
                                                         const float* __restrict__ bias,
                                                         const float* __restrict__ slope,
                                                         void* __restrict__ Cv,
                                                         const float* __restrict__ Wns,
                                                         u16* __restrict__ Wnd) {
  constexpr int Kdim = NNODES;
  __shared__ u16 lds[65536];           // 128KB: A [0,32768), B [32768,65536)
  u16* ldsA = lds;
  u16* ldsB = lds + 32768;

  const int tid  = threadIdx.x;
  const int lane = tid & 63;
  const int wid  = tid >> 6;
  const int wr   = wid >> 2;           // 0..1 : 128-row half
  const int wc   = wid & 3;            // 0..3 : 64-col quarter

  // XCD-aware bijective swizzle (256 blocks, 8 XCDs)
  int bid = blockIdx.x;
  int swz = (bid & 7) * 32 + (bid >> 3);
  const int brow = (swz >> 4) * 256;
  const int bcol = (swz & 15) * 256;

  // staging source: thread t -> row t/8, granule (t&7) XOR (row&7)  (pre-swizzled)
  const int srow = tid >> 3;
  const int sg   = ((tid & 7) ^ (srow & 7)) * 8;
  const u16* Asrc0 = A + (size_t)(brow + srow) * Kdim + sg;
  const u16* Bsrc0 = B + (size_t)(bcol + srow) * Kdim + sg;

  // ds_read: lane -> row r16, k-quarter kq; granule g = (ks*4+kq) ^ (r16&7)
  const int r16 = lane & 15, kq = lane >> 4;
  const int g0  = kq ^ (r16 & 7);
  const int gk0 = g0 * 8, gk1 = (g0 ^ 4) * 8;
  const int aBase = wr * 8192 + r16 * 64;
  const int bBase = (wc >> 1) * 8192 + ((wc & 1) * 64 + r16) * 64;

  // W(i+1) conversion: block bid converts 64K f32 (32 chunks x 512thr x float4)
  const size_t cvoff = (size_t)bid * 65536 + tid * 4;
  f32x4 cvA, cvB;

  f32x4 acc[8][4] = {};
  short8 afr[4][2], bfr[2][2][2];

  // prologue: stage B(0), A(0), B(1); VMC(4) certifies tiles' A(0),B(0)
  STAGE_B(0, 0) STAGE_B(0, 1) STAGE_A(0, 0) STAGE_A(0, 1) STAGE_B(1, 0) STAGE_B(1, 1)
  VMC(4);
  __builtin_amdgcn_s_barrier();

  for (int t = 0; t < 31; ++t) {
    const int T = 2 * t;
    PH1(T,     0, 0, STAGE_A(T + 1, 0), ;)
    PH1(T,     0, 1, STAGE_A(T + 1, 1), ;)
    PH1(T,     1, 0, CONVP2,            ;)
    PH1(T,     1, 1, STAGE_B(T + 2, 0), VMP3)
    PH1(T + 1, 0, 0, STAGE_B(T + 2, 1), ;)
    PH1(T + 1, 0, 1, STAGE_A(T + 2, 0), ;)
    PH1(T + 1, 1, 0, STAGE_A(T + 2, 1), ;)
    PH1(T + 1, 1, 1, { STAGE_B(T + 3, 0) STAGE_B(T + 3, 1) }, VMC(4))
  }
  // tail: tiles 62,63 (A(63) staged p0,p1; VMC(0) certifies tile 63)
  PH1(62, 0, 0, STAGE_A(63, 0), ;)
  PH1(62, 0, 1, STAGE_A(63, 1), ;)
  PH1(62, 1, 0, ;, ;)
  PH1(62, 1, 1, ;, VMC(0))
  PH1(63, 0, 0, ;, ;)
  PH1(63, 0, 1, ;, ;)
  PH1(63, 1, 0, ;, ;)
  PH1(63, 1, 1, ;, ;)

  // epilogue: bias + per-feature LeakyReLU
  const int crow0 = brow + wr * 128 + (lane >> 4) * 4;
  const int ccol0 = bcol + wc * 64 + r16;
#pragma unroll
  for (int n = 0; n < 4; ++n) {
    int col = ccol0 + n * 16;
    float bv = bias[col], sv = slope[col];
#pragma unroll
    for (int m = 0; m < 8; ++m) {
      int row0 = crow0 + m * 16;
#pragma unroll
      for (int r = 0; r < 4; ++r) {
        float vv = acc[m][n][r] + bv;
        vv = vv < 0.f ? vv * sv : vv;
        if constexpr (OUTF32) {
          ((float*)Cv)[(size_t)(row0 + r) * NNODES + col] = vv;
        } else {
          ((u16*)Cv)[(size_t)(row0 + r) * NNODES + col] = bf16_rn(vv);
        }
      }
    }
  }
}

extern "C" void kernel_launch(void* const* d_in, const int* in_sizes, int n_in,
                              void* d_out, int out_size, void* d_ws, size_t ws_size,
                              hipStream_t stream) {
  const float* x     = (const float*)d_in[0];
  const float* ln_g  = (const float*)d_in[1];
  const float* ln_b  = (const float*)d_in[2];
  const float* W     = (const float*)d_in[3];
  const float* b     = (const float*)d_in[4];
  const float* slope = (const float*)d_in[5];
  float* out = (float*)d_out;

  char* ws = (char*)d_ws;
  u16* Wbuf0 = (u16*)ws;                                   // 32 MB
  u16* Wbuf1 = (u16*)(ws + (size_t)32 * 1024 * 1024);      // 32 MB
  u16* lnbuf = (u16*)(ws + (size_t)64 * 1024 * 1024);      // 32 MB
  u16* ybuf  = (u16*)(ws + (size_t)96 * 1024 * 1024);      // 32 MB (bf16 y)

  const size_t WN = (size_t)NNODES * NNODES;

  for (int i = 0; i < NBLK; ++i) {
    u16* Wc = (i & 1) ? Wbuf1 : Wbuf0;
    u16* Wn = (i & 1) ? Wbuf0 : Wbuf1;
    if (i == 0)
      prep_kernel<<<dim3(16384 + NBATCH), dim3(256), 0, stream>>>(
          W, Wbuf0, x, ln_g, ln_b, lnbuf);
    else
      ln_bf16_kernel<<<dim3(NBATCH), dim3(256), 0, stream>>>(
          ybuf, ln_g + (size_t)i * NNODES, ln_b + (size_t)i * NNODES, lnbuf);

    if (i == NBLK - 1)
      gemm256_kernel<true, false><<<dim3(256), dim3(512), 0, stream>>>(
          lnbuf, Wc, b + (size_t)i * NNODES, slope + (size_t)i * NNODES,
          (void*)out, nullptr, nullptr);
    else
      gemm256_kernel<false, true><<<dim3(256), dim3(512), 0, stream>>>(
          lnbuf, Wc, b + (size_t)i * NNODES, slope + (size_t)i * NNODES,
          (void*)ybuf, W + WN * (i + 1), Wn);
  }
}